// Round 1
// baseline (277.070 us; speedup 1.0000x reference)
//
#include <hip/hip_runtime.h>
#include <hip/hip_bf16.h>

// Shapes (fixed by the problem): B=4, S=2048, D=1024, H=16, Dh=64.
// Pipeline:
//   1) fused prep: cast resid fp32->bf16; transpose W_Q/K/V -> [3072 n][1024 k];
//      W_out -> W2t [1024 d][1024 hc]   (one kernel, block-id dispatch)
//   2) QKV GEMM: 256x256 8-phase counted-vmcnt schedule (T2+T3+T4+T5),
//      128 KiB dynamic LDS, klo/khi split arenas, XOR-swizzled both sides.
//      Q,K row-major; V transposed [bh][c][s].
//   3) flash attention (fixed-max softmax, raw v_exp_f32, 8-wave/256-q blocks)
//   4) GEMM (old structure, MODE 0): out = Z @ W2t + b_out (fp32)

typedef short s16x8 __attribute__((ext_vector_type(8)));
typedef short s16x4 __attribute__((ext_vector_type(4)));
typedef float f32x4 __attribute__((ext_vector_type(4)));

#define MFMA_BF16(A, B, C) __builtin_amdgcn_mfma_f32_16x16x32_bf16((A), (B), (C), 0, 0, 0)

#if __has_builtin(__builtin_amdgcn_exp2f)
#define EXP2(x) __builtin_amdgcn_exp2f(x)
#else
#define EXP2(x) exp2f(x)
#endif
#if __has_builtin(__builtin_amdgcn_rcpf)
#define RCP(x) __builtin_amdgcn_rcpf(x)
#else
#define RCP(x) (1.0f / (x))
#endif

__device__ __forceinline__ short f2bf(float f) {
    __bf16 h = (__bf16)f;              // RNE convert
    return __builtin_bit_cast(short, h);
}

// async global->LDS, 16 B per lane. LDS dest = wave-uniform base + 16*lane.
__device__ __forceinline__ void gld16(const unsigned short* g, unsigned short* l) {
    __builtin_amdgcn_global_load_lds(
        (const __attribute__((address_space(1))) unsigned int*)g,
        (__attribute__((address_space(3))) unsigned int*)l, 16, 0, 0);
}

// ---------------- 1) fused prep: cast + 4 weight transposes ----------------
// blocks [0,8192): cast; [8192,8448): WQ; +256: WK; +256: WV; +256: Wout.
__global__ __launch_bounds__(256) void prep_fused(
    const float* __restrict__ resid, const float* __restrict__ WQ,
    const float* __restrict__ WK, const float* __restrict__ WV,
    const float* __restrict__ Wout,
    unsigned short* __restrict__ residb, unsigned short* __restrict__ Wqkvt,
    unsigned short* __restrict__ W2t)
{
    const int bid = blockIdx.x;
    if (bid < 8192) {                     // cast 8192*1024 floats, float4 per thread
        const int i = bid * 256 + threadIdx.x;
        const float4 v = ((const float4*)resid)[i];
        s16x4 o;
        o[0] = f2bf(v.x); o[1] = f2bf(v.y); o[2] = f2bf(v.z); o[3] = f2bf(v.w);
        *(s16x4*)(residb + (size_t)i * 4) = o;
        return;
    }
    __shared__ unsigned short tile[64][66];
    const int id2 = bid - 8192;
    const int which = id2 >> 8;           // 0..3
    const int sub = id2 & 255;
    const int tx = threadIdx.x & 63, ty = threadIdx.x >> 6;
    if (which < 3) {                      // W[k][n] 1024x1024 -> Wt[n][k] bf16
        const float* W = which == 0 ? WQ : (which == 1 ? WK : WV);
        unsigned short* Wt = Wqkvt + (size_t)which * 1024 * 1024;
        const int n0 = (sub & 15) * 64, k0 = (sub >> 4) * 64;
        #pragma unroll
        for (int i = ty; i < 64; i += 4)
            tile[i][tx] = (unsigned short)f2bf(W[(size_t)(k0 + i) * 1024 + n0 + tx]);
        __syncthreads();
        #pragma unroll
        for (int i = ty; i < 64; i += 4)
            Wt[(size_t)(n0 + i) * 1024 + k0 + tx] = tile[tx][i];
    } else {                              // W_out[c][h][d] -> W2t[d][h*64+c]
        const int d0 = (sub & 15) * 64, h = sub >> 4;
        #pragma unroll
        for (int c = ty; c < 64; c += 4)
            tile[c][tx] = (unsigned short)f2bf(Wout[(size_t)(c * 16 + h) * 1024 + d0 + tx]);
        __syncthreads();
        #pragma unroll
        for (int i = ty; i < 64; i += 4)
            W2t[(size_t)(d0 + i) * 1024 + h * 64 + tx] = tile[tx][i];
    }
}

// ---------------- 2) QKV GEMM: 256x256 8-phase counted-vmcnt ----------------
// C[8192][3072] = A[8192][1024] * Bt[3072][1024]^T, outputs split Q/K/Vt.
// 8 waves (2M x 4N), per-wave C = 128x64 = acc[8][4] frags.
// LDS (dynamic, 128 KiB): 2 buffers x {A_klo, A_khi, B_klo, B_khi} of 8192 sh
// (256 rows x 32 k, pitch 32 sh). XOR swizzle: 16B slot ^= row&3, applied on
// the DMA *source* address (LDS dest stays linear) and on ds_read offsets.
// Schedule per K-tile t (BK=64): 4 phases {ds_read frags | 2x gld16 prefetch
// of tile t+1 | barrier | 16 MFMA (setprio) | barrier}; counted s_waitcnt
// vmcnt(4) before the klo phases and before the khi phases (never 0 in-loop).
// Ledger: 8 DMA loads outstanding at each wait; oldest 4 = the half being read.
__global__ __launch_bounds__(512, 2) void gemm256_qkv(
    const unsigned short* __restrict__ A,   // residb [8192][1024]
    const unsigned short* __restrict__ Bt,  // Wqkvt  [3072][1024]
    unsigned short* __restrict__ Qb, unsigned short* __restrict__ Kb,
    unsigned short* __restrict__ Vt)
{
    extern __shared__ __align__(16) unsigned short S[];
    constexpr int LDK = 1024, NT = 16;      // K=1024, BK=64
    const int tid = threadIdx.x, lane = tid & 63, w = tid >> 6;
    const int wm = w >> 2, wn = w & 3;      // 2 x 4 waves
    const int quad = lane >> 4, fl = lane & 15;

    // XCD-swizzled tile id: 384 blocks, 48 consecutive tiles per XCD.
    const int wg  = blockIdx.x;
    const int swz = (wg & 7) * 48 + (wg >> 3);
    const int bx  = swz % 12, by = swz / 12;
    const int m0  = by * 256, n0 = bx * 256;

    // --- staging source pointers (per-thread). One gld16 call = 512 thr x 16B
    // = half an arena; j in {0,1} covers rows [0,128) / [128,256).
    // LDS linear slot (row, sl) must hold source k-slot sl ^ (row&3).
    const int srow = (tid >> 6) * 16 + (lane >> 2);
    const int sswz = ((lane & 3) ^ ((lane >> 2) & 3)) * 8;   // elements
    const unsigned short* pa[2];
    const unsigned short* pb[2];
    #pragma unroll
    for (int j = 0; j < 2; ++j) {
        pa[j] = A  + (size_t)(m0 + srow + j * 128) * LDK + sswz;
        pb[j] = Bt + (size_t)(n0 + srow + j * 128) * LDK + sswz;
    }
    const int dst = tid * 8;                 // LDS shorts within arena

    // --- compute-side LDS read offsets (shorts). row&3 == fl&3 for all frags.
    const int sxor = (quad ^ (fl & 3)) * 8;
    const int aoff = (wm * 128 + fl) * 32 + sxor;            // A arenas @0/8192
    const int boff = 16384 + (wn * 64 + fl) * 32 + sxor;     // B arenas @16384/24576

    f32x4 acc[8][4];
    #pragma unroll
    for (int m = 0; m < 8; ++m)
        #pragma unroll
        for (int n = 0; n < 4; ++n) acc[m][n] = (f32x4){0.f, 0.f, 0.f, 0.f};

    // --- prologue: stage tile 0 into buf0, klo group first (vmcnt order!) ---
    gld16(pa[0], S + dst);                   // A_klo
    gld16(pa[1], S + 4096 + dst);
    gld16(pb[0], S + 16384 + dst);           // B_klo
    gld16(pb[1], S + 20480 + dst);
    gld16(pa[0] + 32, S + 8192 + dst);       // A_khi
    gld16(pa[1] + 32, S + 12288 + dst);
    gld16(pb[0] + 32, S + 24576 + dst);      // B_khi
    gld16(pb[1] + 32, S + 28672 + dst);

    for (int t = 0; t < NT; ++t) {
        const int cur = (t & 1) << 15;       // *32768 shorts per buffer
        unsigned short* Sn = S + (cur ^ 32768);
        const unsigned short* Sc = S + cur;
        const int know = (t + 1 < NT) ? (t + 1) * 64 : 0;   // wrap = safe refetch

        // W1: klo(t) landed (own slice), barrier -> all slices visible.
        asm volatile("s_waitcnt vmcnt(4)" ::: "memory");
        __builtin_amdgcn_s_barrier();

        s16x8 bf[4], af[4];
        // ---- ph0: ks=0, mi 0-3 ----
        #pragma unroll
        for (int ni = 0; ni < 4; ++ni) bf[ni] = *(const s16x8*)(Sc + boff + ni * 512);
        #pragma unroll
        for (int mi = 0; mi < 4; ++mi) af[mi] = *(const s16x8*)(Sc + aoff + mi * 512);
        gld16(pa[0] + know, Sn + dst);                      // A_klo(t+1)
        gld16(pa[1] + know, Sn + 4096 + dst);
        asm volatile("" ::: "memory");
        __builtin_amdgcn_s_barrier();
        __builtin_amdgcn_s_setprio(1);
        #pragma unroll
        for (int mi = 0; mi < 4; ++mi)
            #pragma unroll
            for (int ni = 0; ni < 4; ++ni)
                acc[mi][ni] = MFMA_BF16(af[mi], bf[ni], acc[mi][ni]);
        __builtin_amdgcn_s_setprio(0);
        asm volatile("" ::: "memory");
        __builtin_amdgcn_s_barrier();
        // ---- ph1: ks=0, mi 4-7 (bf ks0 kept in regs) ----
        #pragma unroll
        for (int mi = 0; mi < 4; ++mi) af[mi] = *(const s16x8*)(Sc + aoff + (4 + mi) * 512);
        gld16(pb[0] + know, Sn + 16384 + dst);              // B_klo(t+1)
        gld16(pb[1] + know, Sn + 20480 + dst);
        asm volatile("" ::: "memory");
        __builtin_amdgcn_s_barrier();
        __builtin_amdgcn_s_setprio(1);
        #pragma unroll
        for (int mi = 0; mi < 4; ++mi)
            #pragma unroll
            for (int ni = 0; ni < 4; ++ni)
                acc[4 + mi][ni] = MFMA_BF16(af[mi], bf[ni], acc[4 + mi][ni]);
        __builtin_amdgcn_s_setprio(0);

        // W2: khi(t) landed.
        asm volatile("s_waitcnt vmcnt(4)" ::: "memory");
        __builtin_amdgcn_s_barrier();
        // ---- ph2: ks=1, mi 0-3 ----
        #pragma unroll
        for (int ni = 0; ni < 4; ++ni) bf[ni] = *(const s16x8*)(Sc + 8192 + boff + ni * 512);
        #pragma unroll
        for (int mi = 0; mi < 4; ++mi) af[mi] = *(const s16x8*)(Sc + 8192 + aoff + mi * 512);
        gld16(pa[0] + know + 32, Sn + 8192 + dst);          // A_khi(t+1)
        gld16(pa[1] + know + 32, Sn + 12288 + dst);
        asm volatile("" ::: "memory");
        __builtin_amdgcn_s_barrier();
        __builtin_amdgcn_s_setprio(1);
        #pragma unroll
        for (int mi = 0; mi < 4; ++mi)
            #pragma unroll
            for (int ni = 0; ni < 4; ++ni)
                acc[mi][ni] = MFMA_BF16(af[mi], bf[ni], acc[mi][ni]);
        __builtin_amdgcn_s_setprio(0);
        asm volatile("" ::: "memory");
        __builtin_amdgcn_s_barrier();
        // ---- ph3: ks=1, mi 4-7 ----
        #pragma unroll
        for (int mi = 0; mi < 4; ++mi) af[mi] = *(const s16x8*)(Sc + 8192 + aoff + (4 + mi) * 512);
        gld16(pb[0] + know + 32, Sn + 24576 + dst);         // B_khi(t+1)
        gld16(pb[1] + know + 32, Sn + 28672 + dst);
        asm volatile("" ::: "memory");
        __builtin_amdgcn_s_barrier();
        __builtin_amdgcn_s_setprio(1);
        #pragma unroll
        for (int mi = 0; mi < 4; ++mi)
            #pragma unroll
            for (int ni = 0; ni < 4; ++ni)
                acc[4 + mi][ni] = MFMA_BF16(af[mi], bf[ni], acc[4 + mi][ni]);
        __builtin_amdgcn_s_setprio(0);
        // loop top of t+1 = post-MFMA wait + barrier.
    }

    // ---- epilogue. C/D frag layout: row = quad*4 + r, col = fl. ----
    // Block cols span exactly one of Q/K/V (n0 multiple of 256).
    const int which = n0 >> 10;
    if (which < 2) {
        unsigned short* O = which == 0 ? Qb : Kb;
        const int cbase = (n0 & 1023) + wn * 64;
        #pragma unroll
        for (int m = 0; m < 8; ++m) {
            const int row = m0 + wm * 128 + m * 16 + quad * 4;
            #pragma unroll
            for (int ni = 0; ni < 4; ++ni) {
                const int col = cbase + ni * 16 + fl;
                #pragma unroll
                for (int r = 0; r < 4; ++r)
                    O[(size_t)(row + r) * 1024 + col] = (unsigned short)f2bf(acc[m][ni][r]);
            }
        }
    } else {
        // V transposed: Vt[((b*16+h)*64+c)][s]; r-values s-consecutive -> 8B store
        const int hh = ((n0 - 2048) >> 6) + wn;             // wave-uniform head
        #pragma unroll
        for (int m = 0; m < 8; ++m) {
            const int token = m0 + wm * 128 + m * 16 + quad * 4;
            const int bb = token >> 11, ss = token & 2047;
            #pragma unroll
            for (int ni = 0; ni < 4; ++ni) {
                const int cl = ni * 16 + fl;
                s16x4 pv;
                pv[0] = f2bf(acc[m][ni][0]); pv[1] = f2bf(acc[m][ni][1]);
                pv[2] = f2bf(acc[m][ni][2]); pv[3] = f2bf(acc[m][ni][3]);
                *(s16x4*)(Vt + (size_t)((bb * 16 + hh) * 64 + cl) * 2048 + ss) = pv;
            }
        }
    }
}

// ---------------- 4) bf16 GEMM (old structure): C = A * Bt^T + bias --------
// 128x128 tile, BK=64, 4 waves (2x2), 4x4 frags/wave. Kept for the output
// projection (N=1024 -> only 128 tiles at 256^2, would idle half the GPU).
template <int MODE>
__global__ __launch_bounds__(256, 2) void gemm_bt(
    const unsigned short* __restrict__ A,
    const unsigned short* __restrict__ Bt,
    float* __restrict__ Cf, const float* __restrict__ bias,
    unsigned short* __restrict__ Qb, unsigned short* __restrict__ Kb,
    unsigned short* __restrict__ Vt,
    int M, int N, int K)
{
    __shared__ __align__(16) unsigned short AB[2 * 128 * 72];  // A: 0..9215, B: 9216..
    const int tid  = threadIdx.x;
    const int lane = tid & 63;
    const int w    = tid >> 6;
    const int wm   = w & 1, wn = w >> 1;
    const int quad = lane >> 4, fl = lane & 15;
    const int m0 = blockIdx.y * 128, n0 = blockIdx.x * 128;

    const unsigned short* gp[9];
    unsigned ldso[9];
    #pragma unroll
    for (int i = 0; i < 9; ++i) {
        const int c = i * 256 + tid;
        const int cm = c % 1152;
        const int r = cm / 9, cl0 = cm % 9;
        const int cl = (cl0 == 8) ? 0 : cl0;
        gp[i] = (c < 1152 ? A + (size_t)(m0 + r) * K : Bt + (size_t)(n0 + r) * K) + cl * 8;
        ldso[i] = (unsigned)c * 8u;
    }

    f32x4 acc[4][4];
    #pragma unroll
    for (int i = 0; i < 4; ++i)
        #pragma unroll
        for (int j = 0; j < 4; ++j)
            acc[i][j] = (f32x4){0.f, 0.f, 0.f, 0.f};

    for (int kt = 0; kt < K; kt += 64) {
        __syncthreads();
        #pragma unroll
        for (int i = 0; i < 9; ++i)
            gld16(gp[i] + kt, AB + ldso[i]);
        __syncthreads();
        #pragma unroll
        for (int ko = 0; ko < 2; ++ko) {
            s16x8 af[4], bf[4];
            #pragma unroll
            for (int mi = 0; mi < 4; ++mi)
                af[mi] = *(const s16x8*)(AB + (wm * 64 + mi * 16 + fl) * 72 + ko * 32 + quad * 8);
            #pragma unroll
            for (int ni = 0; ni < 4; ++ni)
                bf[ni] = *(const s16x8*)(AB + 9216 + (wn * 64 + ni * 16 + fl) * 72 + ko * 32 + quad * 8);
            #pragma unroll
            for (int mi = 0; mi < 4; ++mi)
                #pragma unroll
                for (int ni = 0; ni < 4; ++ni)
                    acc[mi][ni] = MFMA_BF16(af[mi], bf[ni], acc[mi][ni]);
        }
    }

    if (MODE == 0) {
        #pragma unroll
        for (int ni = 0; ni < 4; ++ni) {
            const int col = n0 + wn * 64 + ni * 16 + fl;
            const float bv = bias[col];
            #pragma unroll
            for (int mi = 0; mi < 4; ++mi) {
                const int row = m0 + wm * 64 + mi * 16 + quad * 4;
                #pragma unroll
                for (int r = 0; r < 4; ++r)
                    Cf[(size_t)(row + r) * N + col] = acc[mi][ni][r] + bv;
            }
        }
    } else {
        #pragma unroll
        for (int ni = 0; ni < 4; ++ni) {
            const int colg = n0 + wn * 64 + ni * 16 + fl;
            #pragma unroll
            for (int mi = 0; mi < 4; ++mi) {
                const int token = m0 + wm * 64 + mi * 16 + quad * 4;
                if (n0 < 1024) {
                    #pragma unroll
                    for (int r = 0; r < 4; ++r)
                        Qb[(size_t)(token + r) * 1024 + colg] = (unsigned short)f2bf(acc[mi][ni][r]);
                } else if (n0 < 2048) {
                    #pragma unroll
                    for (int r = 0; r < 4; ++r)
                        Kb[(size_t)(token + r) * 1024 + (colg - 1024)] = (unsigned short)f2bf(acc[mi][ni][r]);
                } else {
                    const int cc = colg - 2048;
                    const int hh = cc >> 6, cl = cc & 63;
                    const int bb = token >> 11, ss = token & 2047;
                    s16x4 pv;
                    pv[0] = f2bf(acc[mi][ni][0]); pv[1] = f2bf(acc[mi][ni][1]);
                    pv[2] = f2bf(acc[mi][ni][2]); pv[3] = f2bf(acc[mi][ni][3]);
                    *(s16x4*)(Vt + (size_t)((bb * 16 + hh) * 64 + cl) * 2048 + ss) = pv;
                }
            }
        }
    }
}

// ---------------- 3) attention tile body (DIAG templated) ----------------
template <bool DIAG>
__device__ __forceinline__ void attn_tile(
    int s0, int wl, int wq0, int fl, int quad,
    const unsigned short* __restrict__ KV, const unsigned short* __restrict__ Vs,
    unsigned short* __restrict__ PbW,
    const s16x8 (&qfr)[2][2], f32x4 (&zt)[2][4], float (&ls)[2])
{
    const float SC = 0.18033688011112042f;   // (1/sqrt(64)) * log2(e)
    const float M  = 32.0f;                  // fixed softmax shift
    #pragma unroll
    for (int c4 = 0; c4 < 4; ++c4) {
        if (DIAG && c4 > wl) break;          // wave-uniform causal skip
        #pragma unroll
        for (int e = 0; e < 2; ++e) {
            const int f = 2 * c4 + e;
            const unsigned short* Krow = KV + (f * 16 + fl) * 72;
            const s16x8 kf0 = *(const s16x8*)(Krow + quad * 8);
            const s16x8 kf1 = *(const s16x8*)(Krow + 32 + quad * 8);
            #pragma unroll
            for (int g = 0; g < 2; ++g) {
                unsigned short* pw = PbW + (g * 16 + fl) * 36 + e * 16 + quad * 4;
                if (DIAG && f > 2 * wl + g) { // fully masked frag: zero-fill
                    *(s16x4*)pw = (s16x4){0, 0, 0, 0};
                } else {
                    f32x4 z = (f32x4){0.f, 0.f, 0.f, 0.f};
                    z = MFMA_BF16(kf0, qfr[g][0], z);
                    z = MFMA_BF16(kf1, qfr[g][1], z);
                    float p[4];
                    #pragma unroll
                    for (int r = 0; r < 4; ++r) {
                        float arg = fmaf(z[r], SC, -M);
                        if (DIAG && f == 2 * wl + g) {   // diagonal frag only
                            const int s = s0 + f * 16 + quad * 4 + r;
                            const int qi = wq0 + g * 16 + fl;
                            if (s > qi) arg = -100.f;    // exp2 -> ~0
                        }
                        p[r] = EXP2(arg);
                    }
                    ls[g] += (p[0] + p[1]) + (p[2] + p[3]);
                    s16x4 pk;
                    pk[0] = f2bf(p[0]); pk[1] = f2bf(p[1]);
                    pk[2] = f2bf(p[2]); pk[3] = f2bf(p[3]);
                    *(s16x4*)pw = pk;
                }
            }
        }
        // PV for this 32-s chunk
        const s16x8 pf0 = *(const s16x8*)(PbW + fl * 36 + quad * 8);
        const s16x8 pf1 = *(const s16x8*)(PbW + (16 + fl) * 36 + quad * 8);
        #pragma unroll
        for (int mf = 0; mf < 4; ++mf) {
            const s16x8 vf = *(const s16x8*)(Vs + (mf * 16 + fl) * 136 + c4 * 32 + quad * 8);
            zt[0][mf] = MFMA_BF16(vf, pf0, zt[0][mf]);
            zt[1][mf] = MFMA_BF16(vf, pf1, zt[1][mf]);
        }
    }
}

// ---------------- 3) causal flash attention, fixed-max softmax ----------------
__global__ __launch_bounds__(512, 4) void attn_causal(
    const unsigned short* __restrict__ Qb,
    const unsigned short* __restrict__ Kb,
    const unsigned short* __restrict__ Vt,
    unsigned short* __restrict__ Zb)
{
    __shared__ __align__(16) unsigned short KV[17920];      // K: 128x72 sh, V: 64x136 sh
    __shared__ __align__(16) unsigned short Pb[8][32 * 36]; // per wave [32 q][32 s + pad]
    const int tid = threadIdx.x, lane = tid & 63, w = tid >> 6;
    const int quad = lane >> 4, fl = lane & 15;
    const int lid = blockIdx.x;
    const int g8 = lid >> 6;
    const int qb = g8 < 4 ? 7 - g8 : g8 - 4;    // {7,6,5,4,0,1,2,3}
    const int bh = lid & 63, b = bh >> 4, h = bh & 15;
    const int wq0 = qb * 256 + w * 32;          // wave's first q row
    const int wl = w & 3;                       // wave's slot within its 128-q half
    const int dt = 2 * qb + (w >> 2);           // wave's diagonal tile index

    const unsigned short* Kbase = Kb + (size_t)b * 2048 * 1024 + h * 64;
    const unsigned short* Vbase = Vt + (size_t)bh * 64 * 2048;
    unsigned short* PbW = Pb[w];
    const unsigned short* Vs = KV + 9216;

    // Q fragments: [g][half]
    s16x8 qfr[2][2];
    #pragma unroll
    for (int g = 0; g < 2; ++g) {
        const unsigned short* Qrow = Qb + (size_t)(b * 2048 + wq0 + g * 16 + fl) * 1024 + h * 64;
        qfr[g][0] = *(const s16x8*)(Qrow + quad * 8);
        qfr[g][1] = *(const s16x8*)(Qrow + 32 + quad * 8);
    }

    // Staging map: 35 chunks over 8 waves (waves 0-2 get 5, rest 4).
    const unsigned short* gsp[5];
    int sadv[5];
    unsigned ldsb[5];
    #pragma unroll
    for (int i = 0; i < 5; ++i) {
        const int W = w + 8 * i;
        if (W < 35) {
            const int c = W * 64 + lane;
            if (c < 1152) {
                const int r = c / 9, cl0 = c % 9;
                const int cl = (cl0 == 8) ? 0 : cl0;
                gsp[i] = Kbase + r * 1024 + cl * 8;  sadv[i] = 128 * 1024;
            } else {
                const int cc = c - 1152;
                const int r = cc / 17, cl0 = cc % 17;
                const int cl = (cl0 == 16) ? 0 : cl0;
                gsp[i] = Vbase + r * 2048 + cl * 8;  sadv[i] = 128;
            }
            ldsb[i] = (unsigned)c * 8u;
        }
    }

    f32x4 zt[2][4];                              // [g][mf] in AGPRs
    #pragma unroll
    for (int g = 0; g < 2; ++g)
        #pragma unroll
        for (int mf = 0; mf < 4; ++mf) zt[g][mf] = (f32x4){0.f, 0.f, 0.f, 0.f};
    float ls[2] = {0.f, 0.f};
    const int ntiles = 2 * qb + 2;

    for (int kt = 0; kt < ntiles; ++kt) {
        __syncthreads();
        #pragma unroll
        for (int i = 0; i < 5; ++i)
            if (w + 8 * i < 35)
                gld16(gsp[i], KV + ldsb[i]);
        #pragma unroll
        for (int i = 0; i < 5; ++i)
            if (w + 8 * i < 35)
                gsp[i] += sadv[i];
        __syncthreads();

        if (kt < dt) {
            attn_tile<false>(kt << 7, wl, wq0, fl, quad, KV, Vs, PbW, qfr, zt, ls);
        } else if (kt == dt) {
            attn_tile<true>(kt << 7, wl, wq0, fl, quad, KV, Vs, PbW, qfr, zt, ls);
        }
    }
    // ---- normalize + store Z ----
    #pragma unroll
    for (int g = 0; g < 2; ++g) {
        float lt = ls[g];
        lt += __shfl_xor(lt, 16);
        lt += __shfl_xor(lt, 32);
        const float inv = RCP(lt);
        unsigned short* Zrow = Zb + (size_t)(b * 2048 + wq0 + g * 16 + fl) * 1024 + h * 64;
        #pragma unroll
        for (int mf = 0; mf < 4; ++mf) {
            s16x4 o;
            o[0] = f2bf(zt[g][mf][0] * inv); o[1] = f2bf(zt[g][mf][1] * inv);
            o[2] = f2bf(zt[g][mf][2] * inv); o[3] = f2bf(zt[g][mf][3] * inv);
            *(s16x4*)(Zrow + mf * 16 + quad * 4) = o;
        }
    }
}

// ---------------- launch ----------------
extern "C" void kernel_launch(void* const* d_in, const int* in_sizes, int n_in,
                              void* d_out, int out_size, void* d_ws, size_t ws_size,
                              hipStream_t stream) {
    const float* resid = (const float*)d_in[0];
    const float* WQ    = (const float*)d_in[1];
    const float* WK    = (const float*)d_in[2];
    const float* WV    = (const float*)d_in[3];
    const float* Wout  = (const float*)d_in[4];
    const float* bout  = (const float*)d_in[5];
    float* out = (float*)d_out;

    char* p = (char*)d_ws;
    auto alloc = [&](size_t bytes) { void* r = (void*)p; p += (bytes + 255) & ~(size_t)255; return r; };
    unsigned short* residb = (unsigned short*)alloc(8192ull * 1024 * 2);
    unsigned short* Wqkvt  = (unsigned short*)alloc(3072ull * 1024 * 2);
    unsigned short* W2t    = (unsigned short*)alloc(1024ull * 1024 * 2);
    unsigned short* Qbuf   = (unsigned short*)alloc(8192ull * 1024 * 2);
    unsigned short* Kbuf   = (unsigned short*)alloc(8192ull * 1024 * 2);
    unsigned short* Vtb    = (unsigned short*)alloc(64ull * 64 * 2048 * 2);
    unsigned short* Zbuf   = (unsigned short*)alloc(8192ull * 1024 * 2);

    static bool s_attr = false;
    if (!s_attr) {                           // host-side attr set; graph-capture-safe
        hipFuncSetAttribute(reinterpret_cast<const void*>(gemm256_qkv),
                            hipFuncAttributeMaxDynamicSharedMemorySize, 131072);
        s_attr = true;
    }

    prep_fused<<<9216, 256, 0, stream>>>(resid, WQ, WK, WV, Wout, residb, Wqkvt, W2t);
    gemm256_qkv<<<384, 512, 131072, stream>>>(residb, Wqkvt, Qbuf, Kbuf, Vtb);
    attn_causal<<<512, 512, 0, stream>>>(Qbuf, Kbuf, Vtb, Zbuf);
    gemm_bt<0><<<dim3(8, 64), 256, 0, stream>>>(Zbuf, W2t, out, bout,
                                                nullptr, nullptr, nullptr, 8192, 1024, 1024);
}

// Round 2
// 263.485 us; speedup vs baseline: 1.0516x; 1.0516x over previous
//
#include <hip/hip_runtime.h>
#include <hip/hip_bf16.h>

// Shapes (fixed by the problem): B=4, S=2048, D=1024, H=16, Dh=64.
// Pipeline:
//   1) fused prep: cast resid fp32->bf16; transpose W_Q/K/V -> [3072 n][1024 k];
//      W_out -> W2t [1024 d][1024 hc]   (one kernel, block-id dispatch)
//   2) QKV GEMM: 128x256 tile, 2-phase-per-K-tile counted-vmcnt schedule,
//      96 KiB dynamic LDS, klo/khi arenas, XOR swizzle key (row>>1)&3
//      (2-way = free). 768 blocks = 3 clean rounds. V transposed [bh][c][s].
//   3) flash attention (fixed-max softmax, raw v_exp_f32, 8-wave/256-q blocks)
//   4) GEMM (old structure, MODE 0): out = Z @ W2t + b_out (fp32)

typedef short s16x8 __attribute__((ext_vector_type(8)));
typedef short s16x4 __attribute__((ext_vector_type(4)));
typedef float f32x4 __attribute__((ext_vector_type(4)));

#define MFMA_BF16(A, B, C) __builtin_amdgcn_mfma_f32_16x16x32_bf16((A), (B), (C), 0, 0, 0)

#if __has_builtin(__builtin_amdgcn_exp2f)
#define EXP2(x) __builtin_amdgcn_exp2f(x)
#else
#define EXP2(x) exp2f(x)
#endif
#if __has_builtin(__builtin_amdgcn_rcpf)
#define RCP(x) __builtin_amdgcn_rcpf(x)
#else
#define RCP(x) (1.0f / (x))
#endif

__device__ __forceinline__ short f2bf(float f) {
    __bf16 h = (__bf16)f;              // RNE convert
    return __builtin_bit_cast(short, h);
}

// async global->LDS, 16 B per lane. LDS dest = wave-uniform base + 16*lane.
__device__ __forceinline__ void gld16(const unsigned short* g, unsigned short* l) {
    __builtin_amdgcn_global_load_lds(
        (const __attribute__((address_space(1))) unsigned int*)g,
        (__attribute__((address_space(3))) unsigned int*)l, 16, 0, 0);
}

// ---------------- 1) fused prep: cast + 4 weight transposes ----------------
// blocks [0,8192): cast; [8192,8448): WQ; +256: WK; +256: WV; +256: Wout.
__global__ __launch_bounds__(256) void prep_fused(
    const float* __restrict__ resid, const float* __restrict__ WQ,
    const float* __restrict__ WK, const float* __restrict__ WV,
    const float* __restrict__ Wout,
    unsigned short* __restrict__ residb, unsigned short* __restrict__ Wqkvt,
    unsigned short* __restrict__ W2t)
{
    const int bid = blockIdx.x;
    if (bid < 8192) {                     // cast 8192*1024 floats, float4 per thread
        const int i = bid * 256 + threadIdx.x;
        const float4 v = ((const float4*)resid)[i];
        s16x4 o;
        o[0] = f2bf(v.x); o[1] = f2bf(v.y); o[2] = f2bf(v.z); o[3] = f2bf(v.w);
        *(s16x4*)(residb + (size_t)i * 4) = o;
        return;
    }
    __shared__ unsigned short tile[64][66];
    const int id2 = bid - 8192;
    const int which = id2 >> 8;           // 0..3
    const int sub = id2 & 255;
    const int tx = threadIdx.x & 63, ty = threadIdx.x >> 6;
    if (which < 3) {                      // W[k][n] 1024x1024 -> Wt[n][k] bf16
        const float* W = which == 0 ? WQ : (which == 1 ? WK : WV);
        unsigned short* Wt = Wqkvt + (size_t)which * 1024 * 1024;
        const int n0 = (sub & 15) * 64, k0 = (sub >> 4) * 64;
        #pragma unroll
        for (int i = ty; i < 64; i += 4)
            tile[i][tx] = (unsigned short)f2bf(W[(size_t)(k0 + i) * 1024 + n0 + tx]);
        __syncthreads();
        #pragma unroll
        for (int i = ty; i < 64; i += 4)
            Wt[(size_t)(n0 + i) * 1024 + k0 + tx] = tile[tx][i];
    } else {                              // W_out[c][h][d] -> W2t[d][h*64+c]
        const int d0 = (sub & 15) * 64, h = sub >> 4;
        #pragma unroll
        for (int c = ty; c < 64; c += 4)
            tile[c][tx] = (unsigned short)f2bf(Wout[(size_t)(c * 16 + h) * 1024 + d0 + tx]);
        __syncthreads();
        #pragma unroll
        for (int i = ty; i < 64; i += 4)
            W2t[(size_t)(d0 + i) * 1024 + h * 64 + tx] = tile[tx][i];
    }
}

// ---------------- 2) QKV GEMM: 128x256 tile, counted-vmcnt klo/khi ----------
// C[8192][3072] = A[8192][1024] * Bt[3072][1024]^T, outputs split Q/K/Vt.
// 8 waves (2M x 4N), per-wave C = 64x64 = acc[4][4] frags.
// LDS (dynamic, 96 KiB): 2 buffers x {A_klo[128][32], A_khi, B_klo[256][32],
// B_khi} (64-B row pitch). XOR swizzle: 16B slot p at row r holds k-chunk
// p ^ ((r>>1)&3). Frag-read bank groups (fl&1, quad^((fl>>1)&3)) -> 8 groups
// x 2 lanes = 2-way (free). DMA dest linear; swizzle on SOURCE addr + reads.
// Schedule per K-tile t: {W1 vmcnt(3); bar; ds klo frags + issue klo(t+1)x3;
// bar; 16 MFMA kk0} then same for khi. Ledger: 6 outstanding at each wait,
// oldest 3 = the K-half being consumed. Never 0 in-loop; t=15 drains at W2.
__global__ __launch_bounds__(512, 2) void gemm_qkv(
    const unsigned short* __restrict__ A,   // residb [8192][1024]
    const unsigned short* __restrict__ Bt,  // Wqkvt  [3072][1024]
    unsigned short* __restrict__ Qb, unsigned short* __restrict__ Kb,
    unsigned short* __restrict__ Vt)
{
    extern __shared__ __align__(16) unsigned short S[];
    constexpr int LDK = 1024, NT = 16;      // K=1024, BK=64
    const int tid = threadIdx.x, lane = tid & 63, w = tid >> 6;
    const int wm = w >> 2, wn = w & 3;      // 2 x 4 waves
    const int quad = lane >> 4, fl = lane & 15;

    // XCD-swizzled tile id: 768 blocks, 96 consecutive tiles per XCD (768%8==0).
    const int wg  = blockIdx.x;
    const int swz = (wg & 7) * 96 + (wg >> 3);
    const int bx  = swz % 12, by = swz / 12;
    const int m0  = by * 128, n0 = bx * 256;

    // --- staging sources. One gld16 = 512 thr x 16 B = 8 KB (one A-half /
    // half a B-half). thread tid -> arena row tid/4, phys slot tid&3;
    // source k-chunk = (tid&3) ^ ((tid>>3)&3)  [key (row>>1)&3].
    const int srow = tid >> 2;                                  // 0..127
    const int sk   = ((tid & 3) ^ ((tid >> 3) & 3)) * 8;        // shorts
    const unsigned short* pa  = A  + (size_t)(m0 + srow) * LDK + sk;
    const unsigned short* pb0 = Bt + (size_t)(n0 + srow) * LDK + sk;
    const unsigned short* pb1 = Bt + (size_t)(n0 + 128 + srow) * LDK + sk;
    const int dst = tid * 8;                 // LDS shorts within arena

    // --- compute-side LDS read offsets (shorts). key = (fl>>1)&3 for all frags.
    const int sx   = (quad ^ ((fl >> 1) & 3)) * 8;
    const int arow = (wm * 64 + fl) * 32 + sx;           // A_klo@0, A_khi@4096
    const int brow = 8192 + (wn * 64 + fl) * 32 + sx;    // B_klo@8192, B_khi@16384

    f32x4 acc[4][4];
    #pragma unroll
    for (int m = 0; m < 4; ++m)
        #pragma unroll
        for (int n = 0; n < 4; ++n) acc[m][n] = (f32x4){0.f, 0.f, 0.f, 0.f};

    // --- prologue: stage tile 0 into buf0, klo group (3) then khi group (3) ---
    gld16(pa,       S + dst);                // A_klo
    gld16(pb0,      S + 8192 + dst);         // B_klo rows 0-127
    gld16(pb1,      S + 12288 + dst);        // B_klo rows 128-255
    gld16(pa + 32,  S + 4096 + dst);         // A_khi
    gld16(pb0 + 32, S + 16384 + dst);        // B_khi rows 0-127
    gld16(pb1 + 32, S + 20480 + dst);        // B_khi rows 128-255

    for (int t = 0; t < NT; ++t) {
        unsigned short* Sc = S + (t & 1) * 24576;
        unsigned short* Sn = S + ((t & 1) ^ 1) * 24576;
        const int ka = (t + 1) * 64;         // prefetch source k offset
        const bool pf = (t + 1 < NT);

        // W1: klo(t) landed (oldest 3 of 6).
        asm volatile("s_waitcnt vmcnt(3)" ::: "memory");
        __builtin_amdgcn_s_barrier();

        s16x8 af[4], bfr[4];
        // ---- phase kk=0 ----
        #pragma unroll
        for (int mi = 0; mi < 4; ++mi) af[mi]  = *(const s16x8*)(Sc + arow + mi * 512);
        #pragma unroll
        for (int ni = 0; ni < 4; ++ni) bfr[ni] = *(const s16x8*)(Sc + brow + ni * 512);
        if (pf) {
            gld16(pa + ka,  Sn + dst);                   // A_klo(t+1)
            gld16(pb0 + ka, Sn + 8192 + dst);            // B_klo(t+1)
            gld16(pb1 + ka, Sn + 12288 + dst);
        }
        asm volatile("" ::: "memory");
        __builtin_amdgcn_s_barrier();
        __builtin_amdgcn_s_setprio(1);
        #pragma unroll
        for (int mi = 0; mi < 4; ++mi)
            #pragma unroll
            for (int ni = 0; ni < 4; ++ni)
                acc[mi][ni] = MFMA_BF16(af[mi], bfr[ni], acc[mi][ni]);
        __builtin_amdgcn_s_setprio(0);

        // W2: khi(t) landed. Last tile has nothing behind it -> full drain.
        if (pf) asm volatile("s_waitcnt vmcnt(3)" ::: "memory");
        else    asm volatile("s_waitcnt vmcnt(0)" ::: "memory");
        __builtin_amdgcn_s_barrier();
        // ---- phase kk=1 ----
        #pragma unroll
        for (int mi = 0; mi < 4; ++mi) af[mi]  = *(const s16x8*)(Sc + 4096 + arow + mi * 512);
        #pragma unroll
        for (int ni = 0; ni < 4; ++ni) bfr[ni] = *(const s16x8*)(Sc + 8192 + brow + ni * 512);
        if (pf) {
            gld16(pa + ka + 32,  Sn + 4096 + dst);       // A_khi(t+1)
            gld16(pb0 + ka + 32, Sn + 16384 + dst);      // B_khi(t+1)
            gld16(pb1 + ka + 32, Sn + 20480 + dst);
        }
        asm volatile("" ::: "memory");
        __builtin_amdgcn_s_barrier();
        __builtin_amdgcn_s_setprio(1);
        #pragma unroll
        for (int mi = 0; mi < 4; ++mi)
            #pragma unroll
            for (int ni = 0; ni < 4; ++ni)
                acc[mi][ni] = MFMA_BF16(af[mi], bfr[ni], acc[mi][ni]);
        __builtin_amdgcn_s_setprio(0);
        // loop top of t+1 = W1 wait + barrier (keeps ds reads of buf safe).
    }

    // ---- epilogue. C/D frag layout: row = quad*4 + r, col = fl. ----
    // Block cols span exactly one of Q/K/V (n0 multiple of 256).
    const int which = n0 >> 10;
    if (which < 2) {
        unsigned short* O = which == 0 ? Qb : Kb;
        const int cbase = (n0 & 1023) + wn * 64;
        #pragma unroll
        for (int mi = 0; mi < 4; ++mi) {
            const int row = m0 + wm * 64 + mi * 16 + quad * 4;
            #pragma unroll
            for (int ni = 0; ni < 4; ++ni) {
                const int col = cbase + ni * 16 + fl;
                #pragma unroll
                for (int r = 0; r < 4; ++r)
                    O[(size_t)(row + r) * 1024 + col] = (unsigned short)f2bf(acc[mi][ni][r]);
            }
        }
    } else {
        // V transposed: Vt[((b*16+h)*64+c)][s]; r-values s-consecutive -> 8B store
        const int hh = ((n0 - 2048) >> 6) + wn;             // wave-uniform head
        #pragma unroll
        for (int mi = 0; mi < 4; ++mi) {
            const int token = m0 + wm * 64 + mi * 16 + quad * 4;
            const int bb = token >> 11, ss = token & 2047;
            #pragma unroll
            for (int ni = 0; ni < 4; ++ni) {
                const int cl = ni * 16 + fl;
                s16x4 pv;
                pv[0] = f2bf(acc[mi][ni][0]); pv[1] = f2bf(acc[mi][ni][1]);
                pv[2] = f2bf(acc[mi][ni][2]); pv[3] = f2bf(acc[mi][ni][3]);
                *(s16x4*)(Vt + (size_t)((bb * 16 + hh) * 64 + cl) * 2048 + ss) = pv;
            }
        }
    }
}

// ---------------- 4) bf16 GEMM (old structure): C = A * Bt^T + bias --------
// 128x128 tile, BK=64, 4 waves (2x2), 4x4 frags/wave. Kept for the output
// projection (N=1024 -> only 128 tiles at 256-class, would idle the GPU).
template <int MODE>
__global__ __launch_bounds__(256, 2) void gemm_bt(
    const unsigned short* __restrict__ A,
    const unsigned short* __restrict__ Bt,
    float* __restrict__ Cf, const float* __restrict__ bias,
    int M, int N, int K)
{
    __shared__ __align__(16) unsigned short AB[2 * 128 * 72];  // A: 0..9215, B: 9216..
    const int tid  = threadIdx.x;
    const int lane = tid & 63;
    const int w    = tid >> 6;
    const int wm   = w & 1, wn = w >> 1;
    const int quad = lane >> 4, fl = lane & 15;
    const int m0 = blockIdx.y * 128, n0 = blockIdx.x * 128;

    const unsigned short* gp[9];
    unsigned ldso[9];
    #pragma unroll
    for (int i = 0; i < 9; ++i) {
        const int c = i * 256 + tid;
        const int cm = c % 1152;
        const int r = cm / 9, cl0 = cm % 9;
        const int cl = (cl0 == 8) ? 0 : cl0;
        gp[i] = (c < 1152 ? A + (size_t)(m0 + r) * K : Bt + (size_t)(n0 + r) * K) + cl * 8;
        ldso[i] = (unsigned)c * 8u;
    }

    f32x4 acc[4][4];
    #pragma unroll
    for (int i = 0; i < 4; ++i)
        #pragma unroll
        for (int j = 0; j < 4; ++j)
            acc[i][j] = (f32x4){0.f, 0.f, 0.f, 0.f};

    for (int kt = 0; kt < K; kt += 64) {
        __syncthreads();
        #pragma unroll
        for (int i = 0; i < 9; ++i)
            gld16(gp[i] + kt, AB + ldso[i]);
        __syncthreads();
        #pragma unroll
        for (int ko = 0; ko < 2; ++ko) {
            s16x8 af[4], bf[4];
            #pragma unroll
            for (int mi = 0; mi < 4; ++mi)
                af[mi] = *(const s16x8*)(AB + (wm * 64 + mi * 16 + fl) * 72 + ko * 32 + quad * 8);
            #pragma unroll
            for (int ni = 0; ni < 4; ++ni)
                bf[ni] = *(const s16x8*)(AB + 9216 + (wn * 64 + ni * 16 + fl) * 72 + ko * 32 + quad * 8);
            #pragma unroll
            for (int mi = 0; mi < 4; ++mi)
                #pragma unroll
                for (int ni = 0; ni < 4; ++ni)
                    acc[mi][ni] = MFMA_BF16(af[mi], bf[ni], acc[mi][ni]);
        }
    }

    #pragma unroll
    for (int ni = 0; ni < 4; ++ni) {
        const int col = n0 + wn * 64 + ni * 16 + fl;
        const float bv = bias[col];
        #pragma unroll
        for (int mi = 0; mi < 4; ++mi) {
            const int row = m0 + wm * 64 + mi * 16 + quad * 4;
            #pragma unroll
            for (int r = 0; r < 4; ++r)
                Cf[(size_t)(row + r) * N + col] = acc[mi][ni][r] + bv;
        }
    }
}

// ---------------- 3) attention tile body (DIAG templated) ----------------
template <bool DIAG>
__device__ __forceinline__ void attn_tile(
    int s0, int wl, int wq0, int fl, int quad,
    const unsigned short* __restrict__ KV, const unsigned short* __restrict__ Vs,
    unsigned short* __restrict__ PbW,
    const s16x8 (&qfr)[2][2], f32x4 (&zt)[2][4], float (&ls)[2])
{
    const float SC = 0.18033688011112042f;   // (1/sqrt(64)) * log2(e)
    const float M  = 32.0f;                  // fixed softmax shift
    #pragma unroll
    for (int c4 = 0; c4 < 4; ++c4) {
        if (DIAG && c4 > wl) break;          // wave-uniform causal skip
        #pragma unroll
        for (int e = 0; e < 2; ++e) {
            const int f = 2 * c4 + e;
            const unsigned short* Krow = KV + (f * 16 + fl) * 72;
            const s16x8 kf0 = *(const s16x8*)(Krow + quad * 8);
            const s16x8 kf1 = *(const s16x8*)(Krow + 32 + quad * 8);
            #pragma unroll
            for (int g = 0; g < 2; ++g) {
                unsigned short* pw = PbW + (g * 16 + fl) * 36 + e * 16 + quad * 4;
                if (DIAG && f > 2 * wl + g) { // fully masked frag: zero-fill
                    *(s16x4*)pw = (s16x4){0, 0, 0, 0};
                } else {
                    f32x4 z = (f32x4){0.f, 0.f, 0.f, 0.f};
                    z = MFMA_BF16(kf0, qfr[g][0], z);
                    z = MFMA_BF16(kf1, qfr[g][1], z);
                    float p[4];
                    #pragma unroll
                    for (int r = 0; r < 4; ++r) {
                        float arg = fmaf(z[r], SC, -M);
                        if (DIAG && f == 2 * wl + g) {   // diagonal frag only
                            const int s = s0 + f * 16 + quad * 4 + r;
                            const int qi = wq0 + g * 16 + fl;
                            if (s > qi) arg = -100.f;    // exp2 -> ~0
                        }
                        p[r] = EXP2(arg);
                    }
                    ls[g] += (p[0] + p[1]) + (p[2] + p[3]);
                    s16x4 pk;
                    pk[0] = f2bf(p[0]); pk[1] = f2bf(p[1]);
                    pk[2] = f2bf(p[2]); pk[3] = f2bf(p[3]);
                    *(s16x4*)pw = pk;
                }
            }
        }
        // PV for this 32-s chunk
        const s16x8 pf0 = *(const s16x8*)(PbW + fl * 36 + quad * 8);
        const s16x8 pf1 = *(const s16x8*)(PbW + (16 + fl) * 36 + quad * 8);
        #pragma unroll
        for (int mf = 0; mf < 4; ++mf) {
            const s16x8 vf = *(const s16x8*)(Vs + (mf * 16 + fl) * 136 + c4 * 32 + quad * 8);
            zt[0][mf] = MFMA_BF16(vf, pf0, zt[0][mf]);
            zt[1][mf] = MFMA_BF16(vf, pf1, zt[1][mf]);
        }
    }
}

// ---------------- 3) causal flash attention, fixed-max softmax ----------------
__global__ __launch_bounds__(512, 4) void attn_causal(
    const unsigned short* __restrict__ Qb,
    const unsigned short* __restrict__ Kb,
    const unsigned short* __restrict__ Vt,
    unsigned short* __restrict__ Zb)
{
    __shared__ __align__(16) unsigned short KV[17920];      // K: 128x72 sh, V: 64x136 sh
    __shared__ __align__(16) unsigned short Pb[8][32 * 36]; // per wave [32 q][32 s + pad]
    const int tid = threadIdx.x, lane = tid & 63, w = tid >> 6;
    const int quad = lane >> 4, fl = lane & 15;
    const int lid = blockIdx.x;
    const int g8 = lid >> 6;
    const int qb = g8 < 4 ? 7 - g8 : g8 - 4;    // {7,6,5,4,0,1,2,3}
    const int bh = lid & 63, b = bh >> 4, h = bh & 15;
    const int wq0 = qb * 256 + w * 32;          // wave's first q row
    const int wl = w & 3;                       // wave's slot within its 128-q half
    const int dt = 2 * qb + (w >> 2);           // wave's diagonal tile index

    const unsigned short* Kbase = Kb + (size_t)b * 2048 * 1024 + h * 64;
    const unsigned short* Vbase = Vt + (size_t)bh * 64 * 2048;
    unsigned short* PbW = Pb[w];
    const unsigned short* Vs = KV + 9216;

    // Q fragments: [g][half]
    s16x8 qfr[2][2];
    #pragma unroll
    for (int g = 0; g < 2; ++g) {
        const unsigned short* Qrow = Qb + (size_t)(b * 2048 + wq0 + g * 16 + fl) * 1024 + h * 64;
        qfr[g][0] = *(const s16x8*)(Qrow + quad * 8);
        qfr[g][1] = *(const s16x8*)(Qrow + 32 + quad * 8);
    }

    // Staging map: 35 chunks over 8 waves (waves 0-2 get 5, rest 4).
    const unsigned short* gsp[5];
    int sadv[5];
    unsigned ldsb[5];
    #pragma unroll
    for (int i = 0; i < 5; ++i) {
        const int W = w + 8 * i;
        if (W < 35) {
            const int c = W * 64 + lane;
            if (c < 1152) {
                const int r = c / 9, cl0 = c % 9;
                const int cl = (cl0 == 8) ? 0 : cl0;
                gsp[i] = Kbase + r * 1024 + cl * 8;  sadv[i] = 128 * 1024;
            } else {
                const int cc = c - 1152;
                const int r = cc / 17, cl0 = cc % 17;
                const int cl = (cl0 == 16) ? 0 : cl0;
                gsp[i] = Vbase + r * 2048 + cl * 8;  sadv[i] = 128;
            }
            ldsb[i] = (unsigned)c * 8u;
        }
    }

    f32x4 zt[2][4];                              // [g][mf] in AGPRs
    #pragma unroll
    for (int g = 0; g < 2; ++g)
        #pragma unroll
        for (int mf = 0; mf < 4; ++mf) zt[g][mf] = (f32x4){0.f, 0.f, 0.f, 0.f};
    float ls[2] = {0.f, 0.f};
    const int ntiles = 2 * qb + 2;

    for (int kt = 0; kt < ntiles; ++kt) {
        __syncthreads();
        #pragma unroll
        for (int i = 0; i < 5; ++i)
            if (w + 8 * i < 35)
                gld16(gsp[i], KV + ldsb[i]);
        #pragma unroll
        for (int i = 0; i < 5; ++i)
            if (w + 8 * i < 35)
                gsp[i] += sadv[i];
        __syncthreads();

        if (kt < dt) {
            attn_tile<false>(kt << 7, wl, wq0, fl, quad, KV, Vs, PbW, qfr, zt, ls);
        } else if (kt == dt) {
            attn_tile<true>(kt << 7, wl, wq0, fl, quad, KV, Vs, PbW, qfr, zt, ls);
        }
    }
    // ---- normalize + store Z ----
    #pragma unroll
    for (int g = 0; g < 2; ++g) {
        float lt = ls[g];
        lt += __shfl_xor(lt, 16);
        lt += __shfl_xor(lt, 32);
        const float inv = RCP(lt);
        unsigned short* Zrow = Zb + (size_t)(b * 2048 + wq0 + g * 16 + fl) * 1024 + h * 64;
        #pragma unroll
        for (int mf = 0; mf < 4; ++mf) {
            s16x4 o;
            o[0] = f2bf(zt[g][mf][0] * inv); o[1] = f2bf(zt[g][mf][1] * inv);
            o[2] = f2bf(zt[g][mf][2] * inv); o[3] = f2bf(zt[g][mf][3] * inv);
            *(s16x4*)(Zrow + mf * 16 + quad * 4) = o;
        }
    }
}

// ---------------- launch ----------------
extern "C" void kernel_launch(void* const* d_in, const int* in_sizes, int n_in,
                              void* d_out, int out_size, void* d_ws, size_t ws_size,
                              hipStream_t stream) {
    const float* resid = (const float*)d_in[0];
    const float* WQ    = (const float*)d_in[1];
    const float* WK    = (const float*)d_in[2];
    const float* WV    = (const float*)d_in[3];
    const float* Wout  = (const float*)d_in[4];
    const float* bout  = (const float*)d_in[5];
    float* out = (float*)d_out;

    char* p = (char*)d_ws;
    auto alloc = [&](size_t bytes) { void* r = (void*)p; p += (bytes + 255) & ~(size_t)255; return r; };
    unsigned short* residb = (unsigned short*)alloc(8192ull * 1024 * 2);
    unsigned short* Wqkvt  = (unsigned short*)alloc(3072ull * 1024 * 2);
    unsigned short* W2t    = (unsigned short*)alloc(1024ull * 1024 * 2);
    unsigned short* Qbuf   = (unsigned short*)alloc(8192ull * 1024 * 2);
    unsigned short* Kbuf   = (unsigned short*)alloc(8192ull * 1024 * 2);
    unsigned short* Vtb    = (unsigned short*)alloc(64ull * 64 * 2048 * 2);
    unsigned short* Zbuf   = (unsigned short*)alloc(8192ull * 1024 * 2);

    static bool s_attr = false;
    if (!s_attr) {                           // host-side attr set; graph-capture-safe
        hipFuncSetAttribute(reinterpret_cast<const void*>(gemm_qkv),
                            hipFuncAttributeMaxDynamicSharedMemorySize, 98304);
        s_attr = true;
    }

    prep_fused<<<9216, 256, 0, stream>>>(resid, WQ, WK, WV, Wout, residb, Wqkvt, W2t);
    gemm_qkv<<<768, 512, 98304, stream>>>(residb, Wqkvt, Qbuf, Kbuf, Vtb);
    attn_causal<<<512, 512, 0, stream>>>(Qbuf, Kbuf, Vtb, Zbuf);
    gemm_bt<0><<<dim3(8, 64), 256, 0, stream>>>(Zbuf, W2t, out, bout, 8192, 1024, 1024);
}